// Round 10
// baseline (40.677 us; speedup 1.0000x reference)
//
#include <hip/hip_runtime.h>
#include <hip/hip_bf16.h>

// Attention: B=512, T=128, C=512, H=64. out[b,t,h] f32.
// R10: R9 + (4 row-groups x 2 n-cols) wave split in the projection K-loop.
// Each wave: 32 rows (2 m-tiles) x 6 n-tiles -> W-fragment LDS reads deduped
// 8x -> 2x (block LDS reads/iter 112KB -> 80KB). Counted-vmcnt pipeline and
// attention phases unchanged.

#define TT 128
#define CC 512
#define HH 64

typedef __attribute__((ext_vector_type(8))) short bf16x8;
typedef __attribute__((ext_vector_type(4))) float f32x4;

__device__ __forceinline__ ushort f2bf(float f) {
    union { float f; unsigned u; } v; v.f = f;
    unsigned r = v.u + 0x7fffu + ((v.u >> 16) & 1u);  // RNE
    return (ushort)(r >> 16);
}

__device__ __forceinline__ void gload_lds16(const void* g, void* l) {
    __builtin_amdgcn_global_load_lds(
        (const __attribute__((address_space(1))) unsigned int*)g,
        (__attribute__((address_space(3))) unsigned int*)l, 16, 0, 0);
}

// ---- wpack: chunk kt stride 8192 ushorts (16KB, last 4KB pad unused) ----
// idx = kt*8192 + (nt*64+lane)*8 + j ;  value = W_{nt>>2}[h][c],
// h = (nt&3)*16 + (lane&15), c = kt*32 + (lane>>4)*8 + j
__global__ void wpack_kernel(const float* __restrict__ wq,
                             const float* __restrict__ wk,
                             const float* __restrict__ wv,
                             ushort* __restrict__ wpk) {
    int p = blockIdx.x * 256 + threadIdx.x;   // 0..98303
    int j  = p & 7;
    int l  = (p >> 3) & 63;
    int nt = (p >> 9) % 12;
    int kt = p / (12 * 512);
    int w  = nt >> 2;
    const float* src = (w == 0) ? wq : ((w == 1) ? wk : wv);
    int h = (nt & 3) * 16 + (l & 15);
    int c = kt * 32 + ((l >> 4) << 3) + j;
    wpk[kt * 8192 + ((nt * 64 + l) * 8) + j] = f2bf(src[h * 512 + c]);
}

// ---- fused: one block per batch element; 8 waves; 512 blocks ----
__launch_bounds__(512, 4)
__global__ void attn_fused_kernel(const float* __restrict__ x,
                                  const ushort* __restrict__ wpk,
                                  float* __restrict__ out) {
    // 64 KB LDS union -> 2 blocks/CU.
    // staging:   [0,32768) W dbuf (2x16KB), [32768,65536) x dbuf (2x16KB)
    // attention: [0,16384) qs, [16384,32768) ks, [32768,49152) vst,
    //            ps = [0,32768) overlay.
    __shared__ __align__(16) char smem[65536];
    ushort* qs  = (ushort*)smem;               // [128][64] swizzled col^((t&7)<<3)
    ushort* ks  = (ushort*)(smem + 16384);     // [128][64] swizzled
    ushort* vst = (ushort*)(smem + 32768);     // [64][128] V^T, swizzled t^((h&7)<<3)
    ushort* ps  = (ushort*)smem;               // [128][128] P overlay, swizzled

    const int tid  = threadIdx.x;
    const int wave = tid >> 6;
    const int lane = tid & 63;
    const int lq   = lane >> 4;
    const int lr   = lane & 15;
    const int b    = blockIdx.x;
    const size_t bB = (size_t)b * TT;          // first global row of this batch

    const f32x4 fzero = {0.f, 0.f, 0.f, 0.f};

    // ================= Phase 1: QKV projection =================
    // wave split: rg = wave>>1 (row-group, 32 rows), nc = wave&1 (n-half, 6 nt)
    const int rg = wave >> 1;
    const int nc = wave & 1;
    const int r0 = rg * 32 + lr;               // m-tile 0 row (block-local)
    const int r1 = r0 + 16;                    // m-tile 1 row

    f32x4 acc[2][6];
    #pragma unroll
    for (int i = 0; i < 2; ++i)
        #pragma unroll
        for (int j = 0; j < 6; ++j) acc[i][j] = fzero;

    // every wave issues EXACTLY 4 global_load_lds per stage (2 W + 2 x)
    auto stage = [&](int kt, int s) {
        // W slab 16KB (12KB data + 4KB pad)
        const char* wsrc = (const char*)(wpk + kt * 8192);
        char* wdst = smem + s * 16384;
        #pragma unroll
        for (int p = 0; p < 2; ++p) {
            int off = wave * 2048 + p * 1024;               // uniform in wave
            gload_lds16(wsrc + off + lane * 16, wdst + off);
        }
        // x slab 16KB = 128 rows x 128 B, swizzled source (slot ^ (row&7))
        char* xdst = smem + 32768 + s * 16384;
        #pragma unroll
        for (int p = 0; p < 2; ++p) {
            int uoff = wave * 2048 + p * 1024;              // uniform
            int off  = uoff + lane * 16;                    // per-lane
            int row  = off >> 7;
            int slot = (off >> 4) & 7;
            int g    = slot ^ (row & 7);
            const float* src = x + (bB + row) * CC + kt * 32 + g * 4;
            gload_lds16(src, xdst + uoff);
        }
    };

    stage(0, 0);

    for (int kt = 0; kt < 16; ++kt) {
        const int cur = kt & 1;

        // barrier 1: all waves finished compute(kt-1) -> safe to overwrite
        // buf[cur^1] with stage(kt+1)'s async writes.
        __builtin_amdgcn_s_barrier();

        if (kt + 1 < 16) {
            stage(kt + 1, cur ^ 1);
            // retire stage(kt)'s 4 loads; keep stage(kt+1)'s 4 in flight (T4).
            asm volatile("s_waitcnt vmcnt(4)" ::: "memory");
        } else {
            asm volatile("s_waitcnt vmcnt(0)" ::: "memory");
        }
        __builtin_amdgcn_sched_barrier(0);

        // barrier 2: every wave's stage(kt) data now visible in LDS.
        __builtin_amdgcn_s_barrier();
        __builtin_amdgcn_sched_barrier(0);

        const float* xs = (const float*)(smem + 32768 + cur * 16384);
        // m-tile 0 fragment
        int sa0 = (lq * 2) ^ (r0 & 7);
        int sa1 = (lq * 2 + 1) ^ (r0 & 7);
        f32x4 alo = *(const f32x4*)(xs + r0 * 32 + sa0 * 4);
        f32x4 ahi = *(const f32x4*)(xs + r0 * 32 + sa1 * 4);
        bf16x8 a0;
        a0[0] = (short)f2bf(alo[0]); a0[1] = (short)f2bf(alo[1]);
        a0[2] = (short)f2bf(alo[2]); a0[3] = (short)f2bf(alo[3]);
        a0[4] = (short)f2bf(ahi[0]); a0[5] = (short)f2bf(ahi[1]);
        a0[6] = (short)f2bf(ahi[2]); a0[7] = (short)f2bf(ahi[3]);
        // m-tile 1 fragment
        int sb0 = (lq * 2) ^ (r1 & 7);
        int sb1 = (lq * 2 + 1) ^ (r1 & 7);
        f32x4 blo = *(const f32x4*)(xs + r1 * 32 + sb0 * 4);
        f32x4 bhi = *(const f32x4*)(xs + r1 * 32 + sb1 * 4);
        bf16x8 a1;
        a1[0] = (short)f2bf(blo[0]); a1[1] = (short)f2bf(blo[1]);
        a1[2] = (short)f2bf(blo[2]); a1[3] = (short)f2bf(blo[3]);
        a1[4] = (short)f2bf(bhi[0]); a1[5] = (short)f2bf(bhi[1]);
        a1[6] = (short)f2bf(bhi[2]); a1[7] = (short)f2bf(bhi[3]);

        const ushort* wf = (const ushort*)(smem + cur * 16384);
        #pragma unroll
        for (int nti = 0; nti < 6; ++nti) {
            bf16x8 bb = *(const bf16x8*)(wf + (((nc * 6 + nti) * 64 + lane) * 8));
            acc[0][nti] = __builtin_amdgcn_mfma_f32_16x16x32_bf16(a0, bb, acc[0][nti], 0, 0, 0);
            acc[1][nti] = __builtin_amdgcn_mfma_f32_16x16x32_bf16(a1, bb, acc[1][nti], 0, 0, 0);
        }
    }

    __syncthreads();   // compute(15) done everywhere before overlay writes

    // ---- QKV -> attention LDS (overlays staging buffers) ----
    #pragma unroll
    for (int mt = 0; mt < 2; ++mt)
        #pragma unroll
        for (int nti = 0; nti < 6; ++nti)
            #pragma unroll
            for (int j = 0; j < 4; ++j) {
                int ntg = nc * 6 + nti;
                int t = rg * 32 + mt * 16 + lq * 4 + j;
                int h = (ntg & 3) * 16 + lr;
                ushort v = f2bf(acc[mt][nti][j]);
                if (ntg < 4)      qs[t * 64 + (h ^ ((t & 7) << 3))] = v;
                else if (ntg < 8) ks[t * 64 + (h ^ ((t & 7) << 3))] = v;
                else              vst[h * 128 + (t ^ ((h & 7) << 3))] = v;
            }
    __syncthreads();

    // ================= Phase 2: S = Q K^T, causal softmax =================
    const int row0 = wave * 16;
    f32x4 s[8];
    #pragma unroll
    for (int j = 0; j < 8; ++j) s[j] = fzero;

    #pragma unroll
    for (int kt = 0; kt < 2; ++kt) {
        int h0 = kt * 32 + lq * 8;
        int t  = row0 + lr;
        bf16x8 a = *(const bf16x8*)&qs[t * 64 + (h0 ^ ((t & 7) << 3))];
        #pragma unroll
        for (int nt = 0; nt < 8; ++nt) {
            int sc = nt * 16 + lr;
            bf16x8 bb = *(const bf16x8*)&ks[sc * 64 + (h0 ^ ((sc & 7) << 3))];
            s[nt] = __builtin_amdgcn_mfma_f32_16x16x32_bf16(a, bb, s[nt], 0, 0, 0);
        }
    }

    float rinv[4];
    #pragma unroll
    for (int j = 0; j < 4; ++j) {
        int t = row0 + lq * 4 + j;
        float m = -1e30f;
        #pragma unroll
        for (int nt = 0; nt < 8; ++nt) {
            int sc = nt * 16 + lr;
            float v = s[nt][j] * 0.125f;
            v = (sc <= t) ? v : -1e30f;        // causal mask
            s[nt][j] = v;
            m = fmaxf(m, v);
        }
        m = fmaxf(m, __shfl_xor(m, 1));
        m = fmaxf(m, __shfl_xor(m, 2));
        m = fmaxf(m, __shfl_xor(m, 4));
        m = fmaxf(m, __shfl_xor(m, 8));
        float sum = 0.f;
        #pragma unroll
        for (int nt = 0; nt < 8; ++nt) {
            float p = __expf(s[nt][j] - m);
            s[nt][j] = p;
            sum += p;
        }
        sum += __shfl_xor(sum, 1);
        sum += __shfl_xor(sum, 2);
        sum += __shfl_xor(sum, 4);
        sum += __shfl_xor(sum, 8);
        rinv[j] = 1.0f / sum;                  // deferred normalization
    }

    __syncthreads();   // all qs/ks reads done before P overlay writes

    #pragma unroll
    for (int j = 0; j < 4; ++j) {
        int t = row0 + lq * 4 + j;
        #pragma unroll
        for (int nt = 0; nt < 8; ++nt) {
            int sc = nt * 16 + lr;
            ps[t * 128 + (sc ^ ((t & 7) << 3))] = f2bf(s[nt][j]);
        }
    }
    __syncthreads();

    // ================= Phase 3: O = P V =================
    f32x4 o[4];
    #pragma unroll
    for (int j = 0; j < 4; ++j) o[j] = fzero;

    #pragma unroll
    for (int ksv = 0; ksv < 4; ++ksv) {
        int s0 = ksv * 32 + lq * 8;
        int t  = row0 + lr;
        bf16x8 a = *(const bf16x8*)&ps[t * 128 + (s0 ^ ((t & 7) << 3))];
        #pragma unroll
        for (int nt = 0; nt < 4; ++nt) {
            int h = nt * 16 + lr;
            bf16x8 bb = *(const bf16x8*)&vst[h * 128 + (s0 ^ ((h & 7) << 3))];
            o[nt] = __builtin_amdgcn_mfma_f32_16x16x32_bf16(a, bb, o[nt], 0, 0, 0);
        }
    }

    float* ob = out + (size_t)b * (TT * HH);
    #pragma unroll
    for (int nt = 0; nt < 4; ++nt)
        #pragma unroll
        for (int j = 0; j < 4; ++j) {
            int t = row0 + lq * 4 + j;
            int h = nt * 16 + lr;
            ob[t * HH + h] = o[nt][j] * rinv[j];
        }
}

extern "C" void kernel_launch(void* const* d_in, const int* in_sizes, int n_in,
                              void* d_out, int out_size, void* d_ws, size_t ws_size,
                              hipStream_t stream) {
    const float* x  = (const float*)d_in[0];
    const float* wq = (const float*)d_in[1];
    const float* wk = (const float*)d_in[2];
    const float* wv = (const float*)d_in[3];
    float* o = (float*)d_out;
    ushort* wpk = (ushort*)d_ws;    // 16 chunks x 16KB = 256 KB packed W

    (void)in_sizes; (void)n_in; (void)out_size; (void)ws_size;

    wpack_kernel<<<384, 256, 0, stream>>>(wq, wk, wv, wpk);
    attn_fused_kernel<<<512, 512, 0, stream>>>(x, wpk, o);
}

// Round 11
// 38.843 us; speedup vs baseline: 1.0472x; 1.0472x over previous
//
#include <hip/hip_runtime.h>
#include <hip/hip_bf16.h>

// Attention: B=512, T=128, C=512, H=64. out[b,t,h] f32.
// R11: R9 structure + batched fragment loads. Root cause found in R8-R10:
// compiler allocated VGPR=52 (= acc 48 + ONE 4-reg fragment buffer), so the
// 12 ds_read_b128->MFMA pairs per k-chunk serialized at ~120cy LDS latency
// each. Fix: load all fragments into explicit w[12]/kf[8]/vf[4] register
// arrays (static indices), then issue the MFMAs. Counted-vmcnt staging
// pipeline and all layouts unchanged from R9.

#define TT 128
#define CC 512
#define HH 64

typedef __attribute__((ext_vector_type(8))) short bf16x8;
typedef __attribute__((ext_vector_type(4))) float f32x4;

__device__ __forceinline__ ushort f2bf(float f) {
    union { float f; unsigned u; } v; v.f = f;
    unsigned r = v.u + 0x7fffu + ((v.u >> 16) & 1u);  // RNE
    return (ushort)(r >> 16);
}

__device__ __forceinline__ void gload_lds16(const void* g, void* l) {
    __builtin_amdgcn_global_load_lds(
        (const __attribute__((address_space(1))) unsigned int*)g,
        (__attribute__((address_space(3))) unsigned int*)l, 16, 0, 0);
}

// ---- wpack: chunk kt stride 8192 ushorts (16KB, last 4KB pad unused) ----
// idx = kt*8192 + (nt*64+lane)*8 + j ;  value = W_{nt>>2}[h][c],
// h = (nt&3)*16 + (lane&15), c = kt*32 + (lane>>4)*8 + j
__global__ void wpack_kernel(const float* __restrict__ wq,
                             const float* __restrict__ wk,
                             const float* __restrict__ wv,
                             ushort* __restrict__ wpk) {
    int p = blockIdx.x * 256 + threadIdx.x;   // 0..98303
    int j  = p & 7;
    int l  = (p >> 3) & 63;
    int nt = (p >> 9) % 12;
    int kt = p / (12 * 512);
    int w  = nt >> 2;
    const float* src = (w == 0) ? wq : ((w == 1) ? wk : wv);
    int h = (nt & 3) * 16 + (l & 15);
    int c = kt * 32 + ((l >> 4) << 3) + j;
    wpk[kt * 8192 + ((nt * 64 + l) * 8) + j] = f2bf(src[h * 512 + c]);
}

// ---- fused: one block per batch element; 8 waves; 512 blocks ----
__launch_bounds__(512, 4)
__global__ void attn_fused_kernel(const float* __restrict__ x,
                                  const ushort* __restrict__ wpk,
                                  float* __restrict__ out) {
    // 64 KB LDS union -> 2 blocks/CU.
    // staging:   [0,32768) W dbuf (2x16KB), [32768,65536) x dbuf (2x16KB)
    // attention: [0,16384) qs, [16384,32768) ks, [32768,49152) vst,
    //            ps = [0,32768) overlay.
    __shared__ __align__(16) char smem[65536];
    ushort* qs  = (ushort*)smem;               // [128][64] swizzled col^((t&7)<<3)
    ushort* ks  = (ushort*)(smem + 16384);     // [128][64] swizzled
    ushort* vst = (ushort*)(smem + 32768);     // [64][128] V^T, swizzled t^((h&7)<<3)
    ushort* ps  = (ushort*)smem;               // [128][128] P overlay, swizzled

    const int tid  = threadIdx.x;
    const int wave = tid >> 6;
    const int lane = tid & 63;
    const int lq   = lane >> 4;
    const int lr   = lane & 15;
    const int b    = blockIdx.x;
    const size_t bB = (size_t)b * TT;          // first global row of this batch

    const f32x4 fzero = {0.f, 0.f, 0.f, 0.f};

    // ================= Phase 1: QKV projection =================
    f32x4 acc[12];
    #pragma unroll
    for (int j = 0; j < 12; ++j) acc[j] = fzero;

    // every wave issues EXACTLY 4 global_load_lds per stage (2 W + 2 x)
    auto stage = [&](int kt, int s) {
        // W slab 16KB (12KB data + 4KB pad)
        const char* wsrc = (const char*)(wpk + kt * 8192);
        char* wdst = smem + s * 16384;
        #pragma unroll
        for (int p = 0; p < 2; ++p) {
            int off = wave * 2048 + p * 1024;               // uniform in wave
            gload_lds16(wsrc + off + lane * 16, wdst + off);
        }
        // x slab 16KB = 128 rows x 128 B, swizzled source (slot ^ (row&7))
        char* xdst = smem + 32768 + s * 16384;
        #pragma unroll
        for (int p = 0; p < 2; ++p) {
            int uoff = wave * 2048 + p * 1024;              // uniform
            int off  = uoff + lane * 16;                    // per-lane
            int row  = off >> 7;
            int slot = (off >> 4) & 7;
            int g    = slot ^ (row & 7);
            const float* src = x + (bB + row) * CC + kt * 32 + g * 4;
            gload_lds16(src, xdst + uoff);
        }
    };

    stage(0, 0);

    const int r = wave * 16 + lr;              // block-local row this lane reads
    for (int kt = 0; kt < 16; ++kt) {
        const int cur = kt & 1;

        // barrier 1: all waves finished compute(kt-1) -> safe to overwrite
        // buf[cur^1] with stage(kt+1)'s async writes.
        __builtin_amdgcn_s_barrier();

        if (kt + 1 < 16) {
            stage(kt + 1, cur ^ 1);
            // retire stage(kt)'s 4 loads; keep stage(kt+1)'s 4 in flight (T4).
            asm volatile("s_waitcnt vmcnt(4)" ::: "memory");
        } else {
            asm volatile("s_waitcnt vmcnt(0)" ::: "memory");
        }
        __builtin_amdgcn_sched_barrier(0);

        // barrier 2: every wave's stage(kt) data now visible in LDS.
        __builtin_amdgcn_s_barrier();
        __builtin_amdgcn_sched_barrier(0);

        // ---- batched fragment loads (ILP), then MFMAs ----
        const float* xs = (const float*)(smem + 32768 + cur * 16384);
        int s0 = (lq * 2) ^ (r & 7);
        int s1 = (lq * 2 + 1) ^ (r & 7);
        f32x4 alo = *(const f32x4*)(xs + r * 32 + s0 * 4);
        f32x4 ahi = *(const f32x4*)(xs + r * 32 + s1 * 4);

        const ushort* wf = (const ushort*)(smem + cur * 16384);
        bf16x8 w[12];
        #pragma unroll
        for (int nt = 0; nt < 12; ++nt)
            w[nt] = *(const bf16x8*)(wf + (nt * 64 + lane) * 8);

        bf16x8 a;
        a[0] = (short)f2bf(alo[0]); a[1] = (short)f2bf(alo[1]);
        a[2] = (short)f2bf(alo[2]); a[3] = (short)f2bf(alo[3]);
        a[4] = (short)f2bf(ahi[0]); a[5] = (short)f2bf(ahi[1]);
        a[6] = (short)f2bf(ahi[2]); a[7] = (short)f2bf(ahi[3]);

        #pragma unroll
        for (int nt = 0; nt < 12; ++nt)
            acc[nt] = __builtin_amdgcn_mfma_f32_16x16x32_bf16(a, w[nt], acc[nt], 0, 0, 0);
    }

    __syncthreads();   // compute(15) done everywhere before overlay writes

    // ---- QKV -> attention LDS (overlays staging buffers) ----
    #pragma unroll
    for (int nt = 0; nt < 12; ++nt)
        #pragma unroll
        for (int j = 0; j < 4; ++j) {
            int t = wave * 16 + lq * 4 + j;
            int h = (nt & 3) * 16 + lr;
            ushort v = f2bf(acc[nt][j]);
            if (nt < 4)      qs[t * 64 + (h ^ ((t & 7) << 3))] = v;
            else if (nt < 8) ks[t * 64 + (h ^ ((t & 7) << 3))] = v;
            else             vst[h * 128 + (t ^ ((h & 7) << 3))] = v;
        }
    __syncthreads();

    // ================= Phase 2: S = Q K^T, causal softmax =================
    const int row0 = wave * 16;
    f32x4 s[8];
    #pragma unroll
    for (int j = 0; j < 8; ++j) s[j] = fzero;

    #pragma unroll
    for (int kt = 0; kt < 2; ++kt) {
        int h0 = kt * 32 + lq * 8;
        int t  = row0 + lr;
        bf16x8 a = *(const bf16x8*)&qs[t * 64 + (h0 ^ ((t & 7) << 3))];
        bf16x8 kf[8];
        #pragma unroll
        for (int nt = 0; nt < 8; ++nt) {
            int sc = nt * 16 + lr;
            kf[nt] = *(const bf16x8*)&ks[sc * 64 + (h0 ^ ((sc & 7) << 3))];
        }
        #pragma unroll
        for (int nt = 0; nt < 8; ++nt)
            s[nt] = __builtin_amdgcn_mfma_f32_16x16x32_bf16(a, kf[nt], s[nt], 0, 0, 0);
    }

    float rinv[4];
    #pragma unroll
    for (int j = 0; j < 4; ++j) {
        int t = row0 + lq * 4 + j;
        float m = -1e30f;
        #pragma unroll
        for (int nt = 0; nt < 8; ++nt) {
            int sc = nt * 16 + lr;
            float v = s[nt][j] * 0.125f;
            v = (sc <= t) ? v : -1e30f;        // causal mask
            s[nt][j] = v;
            m = fmaxf(m, v);
        }
        m = fmaxf(m, __shfl_xor(m, 1));
        m = fmaxf(m, __shfl_xor(m, 2));
        m = fmaxf(m, __shfl_xor(m, 4));
        m = fmaxf(m, __shfl_xor(m, 8));
        float sum = 0.f;
        #pragma unroll
        for (int nt = 0; nt < 8; ++nt) {
            float p = __expf(s[nt][j] - m);
            s[nt][j] = p;
            sum += p;
        }
        sum += __shfl_xor(sum, 1);
        sum += __shfl_xor(sum, 2);
        sum += __shfl_xor(sum, 4);
        sum += __shfl_xor(sum, 8);
        rinv[j] = 1.0f / sum;                  // deferred normalization
    }

    __syncthreads();   // all qs/ks reads done before P overlay writes

    #pragma unroll
    for (int j = 0; j < 4; ++j) {
        int t = row0 + lq * 4 + j;
        #pragma unroll
        for (int nt = 0; nt < 8; ++nt) {
            int sc = nt * 16 + lr;
            ps[t * 128 + (sc ^ ((t & 7) << 3))] = f2bf(s[nt][j]);
        }
    }
    __syncthreads();

    // ================= Phase 3: O = P V =================
    f32x4 o[4];
    #pragma unroll
    for (int j = 0; j < 4; ++j) o[j] = fzero;

    #pragma unroll
    for (int ksv = 0; ksv < 4; ++ksv) {
        int s0 = ksv * 32 + lq * 8;
        int t  = row0 + lr;
        bf16x8 a = *(const bf16x8*)&ps[t * 128 + (s0 ^ ((t & 7) << 3))];
        bf16x8 vf[4];
        #pragma unroll
        for (int nt = 0; nt < 4; ++nt) {
            int h = nt * 16 + lr;
            vf[nt] = *(const bf16x8*)&vst[h * 128 + (s0 ^ ((h & 7) << 3))];
        }
        #pragma unroll
        for (int nt = 0; nt < 4; ++nt)
            o[nt] = __builtin_amdgcn_mfma_f32_16x16x32_bf16(a, vf[nt], o[nt], 0, 0, 0);
    }

    float* ob = out + (size_t)b * (TT * HH);
    #pragma unroll
    for (int nt = 0; nt < 4; ++nt)
        #pragma unroll
        for (int j = 0; j < 4; ++j) {
            int t = row0 + lq * 4 + j;
            int h = nt * 16 + lr;
            ob[t * HH + h] = o[nt][j] * rinv[j];
        }
}

extern "C" void kernel_launch(void* const* d_in, const int* in_sizes, int n_in,
                              void* d_out, int out_size, void* d_ws, size_t ws_size,
                              hipStream_t stream) {
    const float* x  = (const float*)d_in[0];
    const float* wq = (const float*)d_in[1];
    const float* wk = (const float*)d_in[2];
    const float* wv = (const float*)d_in[3];
    float* o = (float*)d_out;
    ushort* wpk = (ushort*)d_ws;    // 16 chunks x 16KB = 256 KB packed W

    (void)in_sizes; (void)n_in; (void)out_size; (void)ws_size;

    wpack_kernel<<<384, 256, 0, stream>>>(wq, wk, wv, wpk);
    attn_fused_kernel<<<512, 512, 0, stream>>>(x, wpk, o);
}